// Round 5
// baseline (635.040 us; speedup 1.0000x reference)
//
#include <hip/hip_runtime.h>

#define E_CNT 200000
#define N_CNT 50000

typedef __attribute__((ext_vector_type(8))) unsigned short ushort8;
typedef __attribute__((ext_vector_type(4))) float f32x4;
typedef __bf16 bf16x8 __attribute__((ext_vector_type(8)));

static __device__ __forceinline__ unsigned short f2bf(float f) {
  unsigned int u = __builtin_bit_cast(unsigned int, f);
  u += 0x7FFFu + ((u >> 16) & 1u);
  return (unsigned short)(u >> 16);
}

// W [K][256] f32 (row-major) -> frag-ready bf16: Bp[(kc*16 + F)*64 + lane][8]
// lane holds B[kc*32 + (lane>>4)*8 + j][F*16 + (lane&15)], j=0..7
__global__ void prep_w(const float* __restrict__ W, unsigned short* __restrict__ Bp, int KC) {
  int idx = blockIdx.x * blockDim.x + threadIdx.x;
  int total = KC * 16 * 64;
  if (idx >= total) return;
  int lane = idx & 63;
  int t = idx >> 6;
  int F = t & 15;
  int kc = t >> 4;
  int col = F * 16 + (lane & 15);
  int kb = kc * 32 + (lane >> 4) * 8;
  ushort8 v;
#pragma unroll
  for (int j = 0; j < 8; ++j) v[j] = f2bf(W[(size_t)(kb + j) * 256 + col]);
  *reinterpret_cast<ushort8*>(Bp + (size_t)idx * 8) = v;
}

// f32 -> bf16, 8 elements per thread
__global__ void cvt_bf16(const float* __restrict__ in, unsigned short* __restrict__ outp,
                         int n8) {
  int i = blockIdx.x * blockDim.x + threadIdx.x;
  if (i >= n8) return;
  f32x4 a = *reinterpret_cast<const f32x4*>(in + (size_t)i * 8);
  f32x4 b = *reinterpret_cast<const f32x4*>(in + (size_t)i * 8 + 4);
  ushort8 v;
#pragma unroll
  for (int j = 0; j < 4; ++j) {
    v[j] = f2bf(a[j]);
    v[4 + j] = f2bf(b[j]);
  }
  *reinterpret_cast<ushort8*>(outp + (size_t)i * 8) = v;
}

// ---------- Barrier-free, LDS-free MFMA GEMM ----------
// out[M,256] = relu(concat-input @ W + bias)
// EDGE: row e = [edges[e](f32) | nodes_bf16[s[e]] | nodes_bf16[r[e]] | gl_bf16]  K=896
//       epilogue: nt-store new_edges + atomicAdd into agg[receivers[e]]
// NODE: row n = [agg[n](f32)   | nodes_bf16[n]    | gl_bf16]                    K=640
// Block: 8 waves (2 wm x 4 wn), wave tile 32x64. A-frags loaded DIRECTLY
// global->VGPR (16B contiguous per lane); A reuse across the 4 wn-waves of a
// block is served by L2. B is frag-ready in L2 (Bp). Zero __syncthreads.
template <int NSTEPS, bool EDGE>
__global__ __launch_bounds__(512, 4) void gemm_mlp(
    const float* __restrict__ in0, const unsigned short* __restrict__ nbf,
    const unsigned short* __restrict__ glb, const int* __restrict__ senders,
    const int* __restrict__ receivers, const unsigned short* __restrict__ Bp,
    const float* __restrict__ bias, float* __restrict__ out,
    float* __restrict__ agg, int M) {
  const int tid = threadIdx.x;
  const int lane = tid & 63;
  const int wave = tid >> 6;  // 0..7
  const int wm = wave >> 2;   // 0..1
  const int wn = wave & 3;    // 0..3
  const int q = lane >> 4;    // 0..3  (k-subchunk)
  const int lr = lane & 15;   // row-in-frag
  const int rowW = blockIdx.x * 64 + wm * 32;

  // per-fragment A row pointers (rows rowW+fm*16+lr)
  const float* p0[2];          // f32 segment (edges / agg)
  const unsigned short* p1[2]; // nodes_bf16 (senders / self)
  const unsigned short* p2[2]; // nodes_bf16 (receivers)  [EDGE only]
#pragma unroll
  for (int fm = 0; fm < 2; ++fm) {
    int r = rowW + fm * 16 + lr;
    if (r > M - 1) r = M - 1;
    p0[fm] = in0 + (size_t)r * 256;
    if (EDGE) {
      p1[fm] = nbf + (size_t)senders[r] * 256;
      p2[fm] = nbf + (size_t)receivers[r] * 256;
    } else {
      p1[fm] = nbf + (size_t)r * 256;
      p2[fm] = nbf;  // unused
    }
  }

  f32x4 acc[2][4] = {};

#pragma unroll
  for (int kc = 0; kc < NSTEPS; ++kc) {
    const int seg = kc >> 3;           // 8 kc-steps per 256-wide segment
    const int ko = (kc & 7) * 32 + q * 8;  // element offset within segment

    // ---- A fragments: one 16B load per lane ----
    bf16x8 a[2];
#pragma unroll
    for (int fm = 0; fm < 2; ++fm) {
      if (seg == 0) {  // f32 source, cast to bf16
        f32x4 lo = *reinterpret_cast<const f32x4*>(p0[fm] + ko);
        f32x4 hi = *reinterpret_cast<const f32x4*>(p0[fm] + ko + 4);
        bf16x8 av;
        av[0] = (__bf16)lo[0]; av[1] = (__bf16)lo[1];
        av[2] = (__bf16)lo[2]; av[3] = (__bf16)lo[3];
        av[4] = (__bf16)hi[0]; av[5] = (__bf16)hi[1];
        av[6] = (__bf16)hi[2]; av[7] = (__bf16)hi[3];
        a[fm] = av;
      } else if (EDGE ? (seg == 1) : false) {
        a[fm] = __builtin_bit_cast(bf16x8,
                    *reinterpret_cast<const ushort8*>(p1[fm] + ko));
      } else if (EDGE ? (seg == 2) : (seg == 1)) {
        a[fm] = __builtin_bit_cast(bf16x8,
                    *reinterpret_cast<const ushort8*>((EDGE ? p2[fm] : p1[fm]) + ko));
      } else {  // globals segment (kc&7 gives segment-local kc; DG=128)
        a[fm] = __builtin_bit_cast(bf16x8,
                    *reinterpret_cast<const ushort8*>(glb + ko));
      }
    }

    // ---- B fragments (L2-hot, frag-ready) ----
    bf16x8 b[4];
#pragma unroll
    for (int fn = 0; fn < 4; ++fn) {
      const int F = wn * 4 + fn;
      b[fn] = __builtin_bit_cast(
          bf16x8, *reinterpret_cast<const ushort8*>(
                      Bp + ((size_t)(kc * 16 + F) * 64 + lane) * 8));
    }

#pragma unroll
    for (int fm = 0; fm < 2; ++fm)
#pragma unroll
      for (int fn = 0; fn < 4; ++fn)
        acc[fm][fn] = __builtin_amdgcn_mfma_f32_16x16x32_bf16(
            a[fm], b[fn], acc[fm][fn], 0, 0, 0);
  }

  // ---- epilogue: bias + relu + store (+ fused segment-sum for EDGE) ----
  // D mapping: col = lane&15, row = (lane>>4)*4 + i
  float bcol[4];
#pragma unroll
  for (int fn = 0; fn < 4; ++fn) bcol[fn] = bias[wn * 64 + fn * 16 + lr];
#pragma unroll
  for (int fm = 0; fm < 2; ++fm) {
    int rb = rowW + fm * 16 + q * 4;
#pragma unroll
    for (int i = 0; i < 4; ++i) {
      int gr = rb + i;
      if (gr < M) {
        int rcv = 0;
        if (EDGE) rcv = receivers[gr];
#pragma unroll
        for (int fn = 0; fn < 4; ++fn) {
          int col = wn * 64 + fn * 16 + lr;
          float v = fmaxf(acc[fm][fn][i] + bcol[fn], 0.0f);
          if (EDGE) {
            __builtin_nontemporal_store(v, &out[(size_t)gr * 256 + col]);
            atomicAdd(agg + (size_t)rcv * 256 + col, v);
          } else {
            out[(size_t)gr * 256 + col] = v;
          }
        }
      }
    }
  }
}

// ---------- two-stage column sum (no atomics) ----------
#define CS_PARTS 128
__global__ void colsum_p1(const float* __restrict__ in, float* __restrict__ part, int rows) {
  const int c4 = threadIdx.x & 63;
  const int rg = threadIdx.x >> 6;
  f32x4 s = {0.f, 0.f, 0.f, 0.f};
  for (int r = blockIdx.x * 4 + rg; r < rows; r += CS_PARTS * 4)
    s += *reinterpret_cast<const f32x4*>(in + (size_t)r * 256 + c4 * 4);
  __shared__ f32x4 red[256];
  red[threadIdx.x] = s;
  __syncthreads();
  if (rg == 0) {
    f32x4 r = red[c4] + red[64 + c4] + red[128 + c4] + red[192 + c4];
    *reinterpret_cast<f32x4*>(part + (size_t)blockIdx.x * 256 + c4 * 4) = r;
  }
}

__global__ void colsum_p2(const float* __restrict__ part, float* __restrict__ out) {
  const int c = threadIdx.x;  // 256
  float s = 0.f;
  for (int p = 0; p < CS_PARTS; ++p) s += part[(size_t)p * 256 + c];
  out[c] = s;
}

// new_globals = relu([esum | nsum | globals] @ Wg + bg), fp32
__global__ void global_mlp(const float* __restrict__ esum, const float* __restrict__ nsum,
                           const float* __restrict__ gl, const float* __restrict__ Wg,
                           const float* __restrict__ bg, float* __restrict__ out2) {
  __shared__ float red[512];
  int g = threadIdx.x & 127;
  int kg = threadIdx.x >> 7;
  float acc = 0.f;
  for (int k = kg; k < 640; k += 4) {
    float x = (k < 256) ? esum[k] : (k < 512 ? nsum[k - 256] : gl[k - 512]);
    acc += x * Wg[(size_t)k * 128 + g];
  }
  red[threadIdx.x] = acc;
  __syncthreads();
  if (kg == 0) {
    float r = red[g] + red[128 + g] + red[256 + g] + red[384 + g] + bg[g];
    out2[g] = fmaxf(r, 0.f);
  }
}

extern "C" void kernel_launch(void* const* d_in, const int* in_sizes, int n_in,
                              void* d_out, int out_size, void* d_ws, size_t ws_size,
                              hipStream_t stream) {
  const float* nodes = (const float*)d_in[0];
  const float* edges = (const float*)d_in[1];
  const float* gl = (const float*)d_in[2];
  const int* senders = (const int*)d_in[3];
  const int* receivers = (const int*)d_in[4];
  const float* We = (const float*)d_in[5];
  const float* be = (const float*)d_in[6];
  const float* Wn = (const float*)d_in[7];
  const float* bn = (const float*)d_in[8];
  const float* Wg = (const float*)d_in[9];
  const float* bg = (const float*)d_in[10];

  float* out0 = (float*)d_out;               // new_edges [200000,256]
  float* out1 = out0 + (size_t)E_CNT * 256;  // new_nodes [50000,256]
  float* out2 = out1 + (size_t)N_CNT * 256;  // new_globals [128]

  char* ws = (char*)d_ws;
  size_t o = 0;
  float* agg = (float*)(ws + o);                   o += (size_t)N_CNT * 256 * 4;  // 51.2 MB
  float* esum = (float*)(ws + o);                  o += 1024;
  float* nsum = (float*)(ws + o);                  o += 1024;
  float* partE = (float*)(ws + o);                 o += CS_PARTS * 256 * 4;
  float* partN = (float*)(ws + o);                 o += CS_PARTS * 256 * 4;
  unsigned short* BpE = (unsigned short*)(ws + o); o += 458752;
  unsigned short* BpN = (unsigned short*)(ws + o); o += 327680;
  unsigned short* nbf = (unsigned short*)(ws + o); o += (size_t)N_CNT * 256 * 2;  // 25.6 MB
  unsigned short* glb = (unsigned short*)(ws + o); o += 512;

  // zero agg every call (edge kernel accumulates into it atomically)
  hipMemsetAsync(agg, 0, (size_t)N_CNT * 256 * 4, stream);

  prep_w<<<112, 256, 0, stream>>>(We, BpE, 28);  // K=896
  prep_w<<<80, 256, 0, stream>>>(Wn, BpN, 20);   // K=640
  cvt_bf16<<<(N_CNT * 32 + 255) / 256, 256, 0, stream>>>(nodes, nbf, N_CNT * 32);
  cvt_bf16<<<1, 16, 0, stream>>>(gl, glb, 16);

  gemm_mlp<28, true><<<E_CNT / 64, 512, 0, stream>>>(
      edges, nbf, glb, senders, receivers, BpE, be, out0, agg, E_CNT);

  colsum_p1<<<CS_PARTS, 256, 0, stream>>>(agg, partE, N_CNT);  // == colsum(new_edges)
  colsum_p2<<<1, 256, 0, stream>>>(partE, esum);

  gemm_mlp<20, false><<<(N_CNT + 63) / 64, 512, 0, stream>>>(
      agg, nbf, glb, nullptr, nullptr, BpN, bn, out1, nullptr, N_CNT);

  colsum_p1<<<CS_PARTS, 256, 0, stream>>>(out1, partN, N_CNT);
  colsum_p2<<<1, 256, 0, stream>>>(partN, nsum);

  global_mlp<<<1, 512, 0, stream>>>(esum, nsum, gl, Wg, bg, out2);
}

// Round 6
// 525.323 us; speedup vs baseline: 1.2089x; 1.2089x over previous
//
#include <hip/hip_runtime.h>

#define E_CNT 200000
#define N_CNT 50000

typedef __attribute__((ext_vector_type(8))) unsigned short ushort8;
typedef __attribute__((ext_vector_type(4))) float f32x4;
typedef __bf16 bf16x8 __attribute__((ext_vector_type(8)));

#define WAITVM(N) asm volatile("s_waitcnt vmcnt(" #N ")" ::: "memory")

static __device__ __forceinline__ unsigned short f2bf(float f) {
  unsigned int u = __builtin_bit_cast(unsigned int, f);
  u += 0x7FFFu + ((u >> 16) & 1u);
  return (unsigned short)(u >> 16);
}

// async global->LDS, 16B per lane; LDS dest = uniform base + lane*16
typedef const __attribute__((address_space(1))) void gvoid;
typedef __attribute__((address_space(3))) void lvoid;
static __device__ __forceinline__ void gload_lds16(const void* g, void* l) {
  __builtin_amdgcn_global_load_lds((gvoid*)g, (lvoid*)l, 16, 0, 0);
}

// W [K][256] f32 (row-major) -> frag-ready bf16: Bp[(kc*16 + F)*64 + lane][8]
__global__ void prep_w(const float* __restrict__ W, unsigned short* __restrict__ Bp, int KC) {
  int idx = blockIdx.x * blockDim.x + threadIdx.x;
  int total = KC * 16 * 64;
  if (idx >= total) return;
  int lane = idx & 63;
  int t = idx >> 6;
  int F = t & 15;
  int kc = t >> 4;
  int col = F * 16 + (lane & 15);
  int kb = kc * 32 + (lane >> 4) * 8;
  ushort8 v;
#pragma unroll
  for (int j = 0; j < 8; ++j) v[j] = f2bf(W[(size_t)(kb + j) * 256 + col]);
  *reinterpret_cast<ushort8*>(Bp + (size_t)idx * 8) = v;
}

// ---------- GEMM: out[M,256] = relu(concat-input @ W + bias) ----------
// EDGE: row e = [edges[e] | nodes[s[e]] | nodes[r[e]] | globals] (K=896)
//       epilogue: nt-store new_edges + atomicAdd into agg[receivers[e]]
// NODE: row n = [agg[n] | nodes[n] | globals] (K=640)
// T3+T4 structure: 3-deep LDS buffers staged via global_load_lds, B-frags
// register-prefetched 1 step ahead, counted s_waitcnt vmcnt (never 0 in
// steady state), one raw s_barrier per K-step, no full drains.
template <int NSTEPS, bool EDGE>
__global__ __launch_bounds__(512, 4) void gemm_mlp(
    const float* __restrict__ in0, const float* __restrict__ nodes,
    const float* __restrict__ gl, const int* __restrict__ senders,
    const int* __restrict__ receivers, const unsigned short* __restrict__ Bp,
    const float* __restrict__ bias, float* __restrict__ out,
    float* __restrict__ agg, int M) {
  __shared__ float ldsA[3][64 * 64];  // 3 x 16 KB, [row][64 k-floats], XOR-swizzled

  const int tid = threadIdx.x;
  const int lane = tid & 63;
  const int wave = tid >> 6;  // 0..7
  const int wm = wave >> 2;   // 0..1
  const int wn = wave & 3;    // 0..3
  const int q = lane >> 4;    // 0..3
  const int lr = lane & 15;
  const int row0 = blockIdx.x * 64;

  // staging: wave stages rows [wave*8, wave*8+8) as 2 issues of 4 rows
  int rl[2];
  const float* bp[2][4];
#pragma unroll
  for (int i = 0; i < 2; ++i) {
    rl[i] = wave * 8 + i * 4 + q;
    int e = row0 + rl[i];
    if (e > M - 1) e = M - 1;
    if (EDGE) {
      bp[i][0] = in0 + (size_t)e * 256;
      bp[i][1] = nodes + (size_t)senders[e] * 256;
      bp[i][2] = nodes + (size_t)receivers[e] * 256;
      bp[i][3] = gl;
    } else {
      bp[i][0] = in0 + (size_t)e * 256;
      bp[i][1] = nodes + (size_t)e * 256;
      bp[i][2] = gl;
      bp[i][3] = gl;
    }
  }

  auto stage = [&](int ksi, int bidx) {
#pragma unroll
    for (int i = 0; i < 2; ++i) {
      const float* src = bp[i][ksi >> 2] + ((ksi & 3) << 6) + ((lr ^ (rl[i] & 15)) << 2);
      gload_lds16(src, &ldsA[bidx][(wave * 8 + i * 4) * 64]);
    }
  };

  auto loadB = [&](int ksi, bf16x8 (&dst)[2][4]) {
#pragma unroll
    for (int kk = 0; kk < 2; ++kk) {
      const int kc32 = ksi * 2 + kk;
#pragma unroll
      for (int fn = 0; fn < 4; ++fn) {
        const int F = wn * 4 + fn;
        dst[kk][fn] = __builtin_bit_cast(
            bf16x8, *reinterpret_cast<const ushort8*>(
                        Bp + ((size_t)(kc32 * 16 + F) * 64 + lane) * 8));
      }
    }
  };

  f32x4 acc[2][4] = {};
  bf16x8 bcur[2][4];

  // ---- prologue: S(0), S(1), B(0); retire S(0); align ----
  stage(0, 0);
  stage(1, 1);
  loadB(0, bcur);
  WAITVM(2);  // retires through S(0) regardless of issue interleave
  __builtin_amdgcn_sched_barrier(0);
  __builtin_amdgcn_s_barrier();

#pragma unroll
  for (int t = 0; t < NSTEPS; ++t) {
    const int buf = t % 3;

    bf16x8 bnxt[2][4];
    if (t + 1 < NSTEPS) loadB(t + 1, bnxt);        // 8 VMEM (L2-hot)
    if (t + 2 < NSTEPS) stage(t + 2, (t + 2) % 3); // 2 gload_lds

    // retire previous iteration's leftovers: B(t) + S(t+1); keep this
    // iteration's 10 (B(t+1)+S(t+2)) in flight across the barrier.
    if (t + 2 < NSTEPS) {
      WAITVM(10);
    } else if (t + 1 < NSTEPS) {
      WAITVM(8);
    } else {
      WAITVM(0);
    }
    __builtin_amdgcn_sched_barrier(0);

    // ---- compute on ldsA[buf]: ds_read f32 -> cvt bf16 -> 16 MFMA ----
#pragma unroll
    for (int kk = 0; kk < 2; ++kk) {
      bf16x8 a[2];
#pragma unroll
      for (int fm = 0; fm < 2; ++fm) {
        const int r = wm * 32 + fm * 16 + lr;
        const int x = r & 15;
        const int u0 = kk * 8 + q * 2;
        f32x4 lo = *reinterpret_cast<const f32x4*>(&ldsA[buf][r * 64 + ((u0 ^ x) << 2)]);
        f32x4 hi =
            *reinterpret_cast<const f32x4*>(&ldsA[buf][r * 64 + (((u0 + 1) ^ x) << 2)]);
        bf16x8 av;
        av[0] = (__bf16)lo[0]; av[1] = (__bf16)lo[1];
        av[2] = (__bf16)lo[2]; av[3] = (__bf16)lo[3];
        av[4] = (__bf16)hi[0]; av[5] = (__bf16)hi[1];
        av[6] = (__bf16)hi[2]; av[7] = (__bf16)hi[3];
        a[fm] = av;
      }
#pragma unroll
      for (int fm = 0; fm < 2; ++fm)
#pragma unroll
        for (int fn = 0; fn < 4; ++fn)
          acc[fm][fn] = __builtin_amdgcn_mfma_f32_16x16x32_bf16(
              a[fm], bcur[kk][fn], acc[fm][fn], 0, 0, 0);
    }

    __builtin_amdgcn_sched_barrier(0);
    __builtin_amdgcn_s_barrier();  // publish buf(t+1); reads of buf(t) are done

    if (t + 1 < NSTEPS) {
#pragma unroll
      for (int kk = 0; kk < 2; ++kk)
#pragma unroll
        for (int fn = 0; fn < 4; ++fn) bcur[kk][fn] = bnxt[kk][fn];
    }
  }

  // ---- epilogue: bias + relu + store (+ fused segment-sum for EDGE) ----
  // D mapping: col = lane&15, row = (lane>>4)*4 + i
  float bcol[4];
#pragma unroll
  for (int fn = 0; fn < 4; ++fn) bcol[fn] = bias[wn * 64 + fn * 16 + lr];
#pragma unroll
  for (int fm = 0; fm < 2; ++fm) {
    int rb = row0 + wm * 32 + fm * 16 + q * 4;
#pragma unroll
    for (int i = 0; i < 4; ++i) {
      int gr = rb + i;
      if (gr < M) {
        int rcv = 0;
        if (EDGE) rcv = receivers[gr];
#pragma unroll
        for (int fn = 0; fn < 4; ++fn) {
          int col = wn * 64 + fn * 16 + lr;
          float v = fmaxf(acc[fm][fn][i] + bcol[fn], 0.0f);
          if (EDGE) {
            __builtin_nontemporal_store(v, &out[(size_t)gr * 256 + col]);
            atomicAdd(agg + (size_t)rcv * 256 + col, v);
          } else {
            out[(size_t)gr * 256 + col] = v;
          }
        }
      }
    }
  }
}

// ---------- two-stage column sum (no atomics) ----------
#define CS_PARTS 128
__global__ void colsum_p1(const float* __restrict__ in, float* __restrict__ part, int rows) {
  const int c4 = threadIdx.x & 63;
  const int rg = threadIdx.x >> 6;
  f32x4 s = {0.f, 0.f, 0.f, 0.f};
  for (int r = blockIdx.x * 4 + rg; r < rows; r += CS_PARTS * 4)
    s += *reinterpret_cast<const f32x4*>(in + (size_t)r * 256 + c4 * 4);
  __shared__ f32x4 red[256];
  red[threadIdx.x] = s;
  __syncthreads();
  if (rg == 0) {
    f32x4 r = red[c4] + red[64 + c4] + red[128 + c4] + red[192 + c4];
    *reinterpret_cast<f32x4*>(part + (size_t)blockIdx.x * 256 + c4 * 4) = r;
  }
}

__global__ void colsum_p2(const float* __restrict__ part, float* __restrict__ out) {
  const int c = threadIdx.x;  // 256
  float s = 0.f;
  for (int p = 0; p < CS_PARTS; ++p) s += part[(size_t)p * 256 + c];
  out[c] = s;
}

// new_globals = relu([esum | nsum | globals] @ Wg + bg), fp32
__global__ void global_mlp(const float* __restrict__ esum, const float* __restrict__ nsum,
                           const float* __restrict__ gl, const float* __restrict__ Wg,
                           const float* __restrict__ bg, float* __restrict__ out2) {
  __shared__ float red[512];
  int g = threadIdx.x & 127;
  int kg = threadIdx.x >> 7;
  float acc = 0.f;
  for (int k = kg; k < 640; k += 4) {
    float x = (k < 256) ? esum[k] : (k < 512 ? nsum[k - 256] : gl[k - 512]);
    acc += x * Wg[(size_t)k * 128 + g];
  }
  red[threadIdx.x] = acc;
  __syncthreads();
  if (kg == 0) {
    float r = red[g] + red[128 + g] + red[256 + g] + red[384 + g] + bg[g];
    out2[g] = fmaxf(r, 0.f);
  }
}

extern "C" void kernel_launch(void* const* d_in, const int* in_sizes, int n_in,
                              void* d_out, int out_size, void* d_ws, size_t ws_size,
                              hipStream_t stream) {
  const float* nodes = (const float*)d_in[0];
  const float* edges = (const float*)d_in[1];
  const float* gl = (const float*)d_in[2];
  const int* senders = (const int*)d_in[3];
  const int* receivers = (const int*)d_in[4];
  const float* We = (const float*)d_in[5];
  const float* be = (const float*)d_in[6];
  const float* Wn = (const float*)d_in[7];
  const float* bn = (const float*)d_in[8];
  const float* Wg = (const float*)d_in[9];
  const float* bg = (const float*)d_in[10];

  float* out0 = (float*)d_out;               // new_edges [200000,256]
  float* out1 = out0 + (size_t)E_CNT * 256;  // new_nodes [50000,256]
  float* out2 = out1 + (size_t)N_CNT * 256;  // new_globals [128]

  char* ws = (char*)d_ws;
  size_t o = 0;
  float* agg = (float*)(ws + o);                   o += (size_t)N_CNT * 256 * 4;  // 51.2 MB
  float* esum = (float*)(ws + o);                  o += 1024;
  float* nsum = (float*)(ws + o);                  o += 1024;
  float* partE = (float*)(ws + o);                 o += CS_PARTS * 256 * 4;
  float* partN = (float*)(ws + o);                 o += CS_PARTS * 256 * 4;
  unsigned short* BpE = (unsigned short*)(ws + o); o += 458752;
  unsigned short* BpN = (unsigned short*)(ws + o); o += 327680;

  // zero agg every call (edge kernel accumulates into it atomically)
  hipMemsetAsync(agg, 0, (size_t)N_CNT * 256 * 4, stream);

  prep_w<<<112, 256, 0, stream>>>(We, BpE, 28);  // K=896
  prep_w<<<80, 256, 0, stream>>>(Wn, BpN, 20);   // K=640

  gemm_mlp<14, true><<<E_CNT / 64, 512, 0, stream>>>(
      edges, nodes, gl, senders, receivers, BpE, be, out0, agg, E_CNT);

  colsum_p1<<<CS_PARTS, 256, 0, stream>>>(agg, partE, N_CNT);  // == colsum(new_edges)
  colsum_p2<<<1, 256, 0, stream>>>(partE, esum);

  gemm_mlp<10, false><<<(N_CNT + 63) / 64, 512, 0, stream>>>(
      agg, nodes, gl, nullptr, nullptr, BpN, bn, out1, nullptr, N_CNT);

  colsum_p1<<<CS_PARTS, 256, 0, stream>>>(out1, partN, N_CNT);
  colsum_p2<<<1, 256, 0, stream>>>(partN, nsum);

  global_mlp<<<1, 512, 0, stream>>>(esum, nsum, gl, Wg, bg, out2);
}

// Round 7
// 453.478 us; speedup vs baseline: 1.4004x; 1.1584x over previous
//
#include <hip/hip_runtime.h>

#define E_CNT 200000
#define N_CNT 50000

typedef __attribute__((ext_vector_type(8))) unsigned short ushort8;
typedef __attribute__((ext_vector_type(4))) unsigned short us4;
typedef __attribute__((ext_vector_type(4))) float f32x4;
typedef __bf16 bf16x8 __attribute__((ext_vector_type(8)));

static __device__ __forceinline__ unsigned short f2bf(float f) {
  unsigned int u = __builtin_bit_cast(unsigned int, f);
  u += 0x7FFFu + ((u >> 16) & 1u);
  return (unsigned short)(u >> 16);
}
static __device__ __forceinline__ float bf2f(unsigned short u) {
  unsigned int x = ((unsigned int)u) << 16;
  return __builtin_bit_cast(float, x);
}

// W-block [256][256] f32 (row-major, base pre-offset) -> frag-ready bf16:
// Bp[(kc*16 + F)*64 + lane][8]; lane holds B[kc*32+(lane>>4)*8+j][F*16+(lane&15)]
__global__ void prep_w(const float* __restrict__ W, unsigned short* __restrict__ Bp, int KC) {
  int idx = blockIdx.x * blockDim.x + threadIdx.x;
  int total = KC * 16 * 64;
  if (idx >= total) return;
  int lane = idx & 63;
  int t = idx >> 6;
  int F = t & 15;
  int kc = t >> 4;
  int col = F * 16 + (lane & 15);
  int kb = kc * 32 + (lane >> 4) * 8;
  ushort8 v;
#pragma unroll
  for (int j = 0; j < 8; ++j) v[j] = f2bf(W[(size_t)(kb + j) * 256 + col]);
  *reinterpret_cast<ushort8*>(Bp + (size_t)idx * 8) = v;
}

// c_e = be + g @ We_g ; c_n = bn + g @ Wn_g
__global__ void make_cvec(const float* __restrict__ g, const float* __restrict__ We,
                          const float* __restrict__ be, const float* __restrict__ Wn,
                          const float* __restrict__ bn, float* __restrict__ ce,
                          float* __restrict__ cn) {
  int t = threadIdx.x;  // 512
  int j = t & 255;
  if (t < 256) {
    float s = be[j];
    for (int k = 0; k < 128; ++k) s += g[k] * We[(size_t)(768 + k) * 256 + j];
    ce[j] = s;
  } else {
    float s = bn[j];
    for (int k = 0; k < 128; ++k) s += g[k] * Wn[(size_t)(512 + k) * 256 + j];
    cn[j] = s;
  }
}

// ---------- unified GEMM core: 128-row x 256-col tile, 8 waves, wave 64x64 ----------
// MODE 0 (PROJ): out bf16, frag-swizzled slot = wn*64 + lr*4 + fn  (no bias/relu)
// MODE 1 (EDGE): A=edges K=256; out = relu(acc + ce + Ps[snd] + Pr[rcv]);
//                nt-store + atomicAdd into agg[rcv]
// MODE 2 (NODE): A = [agg | nodes] K=512; out = relu(acc + cn); plain store
template <int NSTEPS, int MODE>
__global__ __launch_bounds__(512, 2) void gemm_core(
    const float* __restrict__ A0, const float* __restrict__ A1,
    const unsigned short* __restrict__ Bp, const unsigned short* __restrict__ P1,
    const unsigned short* __restrict__ P2, const float* __restrict__ cvec,
    const int* __restrict__ senders, const int* __restrict__ receivers,
    float* __restrict__ outF, unsigned short* __restrict__ outP,
    float* __restrict__ agg, int M) {
  __shared__ unsigned short lds[2][128 * 64];  // bf16 A tiles, XOR-swizzled

  const int tid = threadIdx.x;
  const int lane = tid & 63;
  const int wave = tid >> 6;  // 0..7
  const int wm = wave >> 2;   // 0..1
  const int wn = wave & 3;    // 0..3
  const int q = lane >> 4;    // 0..3
  const int lr = lane & 15;
  const int row0 = blockIdx.x * 128;

  // staging: thread stages 16 consecutive floats of one row per K-step
  const int sr = tid >> 2;  // 0..127
  const int sc = tid & 3;   // 16-float chunk
  int er = row0 + sr;
  if (er > M - 1) er = M - 1;
  const float* sbase[2];
  sbase[0] = A0 + (size_t)er * 256;
  sbase[1] = (MODE == 2) ? (A1 + (size_t)er * 256) : sbase[0];

  const int swz = sr & 7;
  const int wbase = sr * 64;
  const int s0 = ((sc * 2) ^ swz) * 8;
  const int s1 = ((sc * 2 + 1) ^ swz) * 8;

  f32x4 acc[4][4] = {};

  // ---- prologue: stage step 0 ----
  {
    const float4* p4 = reinterpret_cast<const float4*>(sbase[0] + sc * 16);
    float fv[16];
    *reinterpret_cast<float4*>(&fv[0]) = p4[0];
    *reinterpret_cast<float4*>(&fv[4]) = p4[1];
    *reinterpret_cast<float4*>(&fv[8]) = p4[2];
    *reinterpret_cast<float4*>(&fv[12]) = p4[3];
    ushort8 w0, w1;
#pragma unroll
    for (int j = 0; j < 8; ++j) {
      w0[j] = f2bf(fv[j]);
      w1[j] = f2bf(fv[8 + j]);
    }
    *reinterpret_cast<ushort8*>(&lds[0][wbase + s0]) = w0;
    *reinterpret_cast<ushort8*>(&lds[0][wbase + s1]) = w1;
  }
  __syncthreads();

#pragma unroll
  for (int ks = 0; ks < NSTEPS; ++ks) {
    const int cc = ks & 1;

    // B-frags for this step (L2-hot)
    bf16x8 bfr[2][4];
#pragma unroll
    for (int kk = 0; kk < 2; ++kk) {
      const int kc32 = ks * 2 + kk;
#pragma unroll
      for (int fn = 0; fn < 4; ++fn) {
        const int F = wn * 4 + fn;
        bfr[kk][fn] = __builtin_bit_cast(
            bf16x8, *reinterpret_cast<const ushort8*>(
                        Bp + ((size_t)(kc32 * 16 + F) * 64 + lane) * 8));
      }
    }

    // next-step A loads to regs
    float4 nf0, nf1, nf2, nf3;
    if (ks + 1 < NSTEPS) {
      const float4* p4 = reinterpret_cast<const float4*>(
          sbase[(ks + 1) >> 2] + ((ks + 1) & 3) * 64 + sc * 16);
      nf0 = p4[0];
      nf1 = p4[1];
      nf2 = p4[2];
      nf3 = p4[3];
    }

    // MFMA on lds[cc]
#pragma unroll
    for (int kk = 0; kk < 2; ++kk) {
      bf16x8 a[4];
#pragma unroll
      for (int fm = 0; fm < 4; ++fm) {
        int r = wm * 64 + fm * 16 + lr;
        int slot = (kk * 4 + q) ^ (r & 7);
        a[fm] = __builtin_bit_cast(
            bf16x8, *reinterpret_cast<const ushort8*>(&lds[cc][r * 64 + slot * 8]));
      }
#pragma unroll
      for (int fm = 0; fm < 4; ++fm)
#pragma unroll
        for (int fn = 0; fn < 4; ++fn)
          acc[fm][fn] = __builtin_amdgcn_mfma_f32_16x16x32_bf16(
              a[fm], bfr[kk][fn], acc[fm][fn], 0, 0, 0);
    }

    // convert + write next tile
    if (ks + 1 < NSTEPS) {
      float fv[16];
      *reinterpret_cast<float4*>(&fv[0]) = nf0;
      *reinterpret_cast<float4*>(&fv[4]) = nf1;
      *reinterpret_cast<float4*>(&fv[8]) = nf2;
      *reinterpret_cast<float4*>(&fv[12]) = nf3;
      ushort8 w0, w1;
#pragma unroll
      for (int j = 0; j < 8; ++j) {
        w0[j] = f2bf(fv[j]);
        w1[j] = f2bf(fv[8 + j]);
      }
      *reinterpret_cast<ushort8*>(&lds[cc ^ 1][wbase + s0]) = w0;
      *reinterpret_cast<ushort8*>(&lds[cc ^ 1][wbase + s1]) = w1;
      __syncthreads();
    }
  }

  // ---- epilogue ----
  // D mapping: col = lane&15 (=lr), row = q*4 + i
  float bcol[4];
  if (MODE != 0) {
#pragma unroll
    for (int fn = 0; fn < 4; ++fn) bcol[fn] = cvec[wn * 64 + fn * 16 + lr];
  }
#pragma unroll
  for (int fm = 0; fm < 4; ++fm) {
    int rb = row0 + wm * 64 + fm * 16 + q * 4;
#pragma unroll
    for (int i = 0; i < 4; ++i) {
      int gr = rb + i;
      if (gr < M) {
        if (MODE == 0) {
          us4 pv;
#pragma unroll
          for (int fn = 0; fn < 4; ++fn) pv[fn] = f2bf(acc[fm][fn][i]);
          *reinterpret_cast<us4*>(outP + (size_t)gr * 256 + wn * 64 + lr * 4) = pv;
        } else if (MODE == 1) {
          int snd = senders[gr], rcv = receivers[gr];
          us4 ps = *reinterpret_cast<const us4*>(P1 + (size_t)snd * 256 + wn * 64 + lr * 4);
          us4 pr = *reinterpret_cast<const us4*>(P2 + (size_t)rcv * 256 + wn * 64 + lr * 4);
#pragma unroll
          for (int fn = 0; fn < 4; ++fn) {
            int col = wn * 64 + fn * 16 + lr;
            float v = fmaxf(acc[fm][fn][i] + bcol[fn] + bf2f(ps[fn]) + bf2f(pr[fn]), 0.0f);
            __builtin_nontemporal_store(v, &outF[(size_t)gr * 256 + col]);
            atomicAdd(agg + (size_t)rcv * 256 + col, v);
          }
        } else {
#pragma unroll
          for (int fn = 0; fn < 4; ++fn) {
            int col = wn * 64 + fn * 16 + lr;
            outF[(size_t)gr * 256 + col] = fmaxf(acc[fm][fn][i] + bcol[fn], 0.0f);
          }
        }
      }
    }
  }
}

// ---------- two-stage column sum (no atomics) ----------
#define CS_PARTS 128
__global__ void colsum_p1(const float* __restrict__ in, float* __restrict__ part, int rows) {
  const int c4 = threadIdx.x & 63;
  const int rg = threadIdx.x >> 6;
  f32x4 s = {0.f, 0.f, 0.f, 0.f};
  for (int r = blockIdx.x * 4 + rg; r < rows; r += CS_PARTS * 4)
    s += *reinterpret_cast<const f32x4*>(in + (size_t)r * 256 + c4 * 4);
  __shared__ f32x4 red[256];
  red[threadIdx.x] = s;
  __syncthreads();
  if (rg == 0) {
    f32x4 r = red[c4] + red[64 + c4] + red[128 + c4] + red[192 + c4];
    *reinterpret_cast<f32x4*>(part + (size_t)blockIdx.x * 256 + c4 * 4) = r;
  }
}

__global__ void colsum_p2(const float* __restrict__ part, float* __restrict__ out) {
  const int c = threadIdx.x;  // 256
  float s = 0.f;
  for (int p = 0; p < CS_PARTS; ++p) s += part[(size_t)p * 256 + c];
  out[c] = s;
}

// new_globals = relu([esum | nsum | globals] @ Wg + bg), fp32
__global__ void global_mlp(const float* __restrict__ esum, const float* __restrict__ nsum,
                           const float* __restrict__ gl, const float* __restrict__ Wg,
                           const float* __restrict__ bg, float* __restrict__ out2) {
  __shared__ float red[512];
  int g = threadIdx.x & 127;
  int kg = threadIdx.x >> 7;
  float acc = 0.f;
  for (int k = kg; k < 640; k += 4) {
    float x = (k < 256) ? esum[k] : (k < 512 ? nsum[k - 256] : gl[k - 512]);
    acc += x * Wg[(size_t)k * 128 + g];
  }
  red[threadIdx.x] = acc;
  __syncthreads();
  if (kg == 0) {
    float r = red[g] + red[128 + g] + red[256 + g] + red[384 + g] + bg[g];
    out2[g] = fmaxf(r, 0.f);
  }
}

extern "C" void kernel_launch(void* const* d_in, const int* in_sizes, int n_in,
                              void* d_out, int out_size, void* d_ws, size_t ws_size,
                              hipStream_t stream) {
  const float* nodes = (const float*)d_in[0];
  const float* edges = (const float*)d_in[1];
  const float* gl = (const float*)d_in[2];
  const int* senders = (const int*)d_in[3];
  const int* receivers = (const int*)d_in[4];
  const float* We = (const float*)d_in[5];
  const float* be = (const float*)d_in[6];
  const float* Wn = (const float*)d_in[7];
  const float* bn = (const float*)d_in[8];
  const float* Wg = (const float*)d_in[9];
  const float* bg = (const float*)d_in[10];

  float* out0 = (float*)d_out;               // new_edges [200000,256]
  float* out1 = out0 + (size_t)E_CNT * 256;  // new_nodes [50000,256]
  float* out2 = out1 + (size_t)N_CNT * 256;  // new_globals [128]

  // agg lives in out1's slot during the edge/colsum phase; the node kernel
  // reads agg[row] and overwrites out1[row] for the same rows only (block-
  // local RAW, ordered by the K-step barriers before the epilogue).
  float* agg = out1;

  char* ws = (char*)d_ws;
  size_t o = 0;
  unsigned short* Ps = (unsigned short*)(ws + o);   o += (size_t)N_CNT * 256 * 2;  // 25.6MB
  unsigned short* Pr = (unsigned short*)(ws + o);   o += (size_t)N_CNT * 256 * 2;  // 25.6MB
  unsigned short* BpEe = (unsigned short*)(ws + o); o += 131072;
  unsigned short* BpPs = (unsigned short*)(ws + o); o += 131072;
  unsigned short* BpPr = (unsigned short*)(ws + o); o += 131072;
  unsigned short* BpN = (unsigned short*)(ws + o);  o += 262144;  // [Wn_e ; Wn_v]
  float* ce = (float*)(ws + o);                     o += 1024;
  float* cn = (float*)(ws + o);                     o += 1024;
  float* esum = (float*)(ws + o);                   o += 1024;
  float* nsum = (float*)(ws + o);                   o += 1024;
  float* partE = (float*)(ws + o);                  o += CS_PARTS * 256 * 4;
  float* partN = (float*)(ws + o);                  o += CS_PARTS * 256 * 4;

  hipMemsetAsync(agg, 0, (size_t)N_CNT * 256 * 4, stream);

  // weight prep: We = [We_e; We_s; We_r; We_g] rows, Wn = [Wn_e; Wn_v; Wn_g]
  prep_w<<<32, 256, 0, stream>>>(We, BpEe, 8);
  prep_w<<<32, 256, 0, stream>>>(We + 256 * 256, BpPs, 8);
  prep_w<<<32, 256, 0, stream>>>(We + 512 * 256, BpPr, 8);
  prep_w<<<32, 256, 0, stream>>>(Wn, BpN, 8);
  prep_w<<<32, 256, 0, stream>>>(Wn + 256 * 256, BpN + 65536, 8);
  make_cvec<<<1, 512, 0, stream>>>(gl, We, be, Wn, bn, ce, cn);

  // node projections: Ps = nodes@We_s, Pr = nodes@We_r (bf16, frag-swizzled)
  gemm_core<4, 0><<<(N_CNT + 127) / 128, 512, 0, stream>>>(
      nodes, nullptr, BpPs, nullptr, nullptr, nullptr, nullptr, nullptr,
      nullptr, Ps, nullptr, N_CNT);
  gemm_core<4, 0><<<(N_CNT + 127) / 128, 512, 0, stream>>>(
      nodes, nullptr, BpPr, nullptr, nullptr, nullptr, nullptr, nullptr,
      nullptr, Pr, nullptr, N_CNT);

  // edge: relu(edges@We_e + Ps[s] + Pr[r] + ce) ; fused atomic segment-sum
  gemm_core<4, 1><<<(E_CNT + 127) / 128, 512, 0, stream>>>(
      edges, nullptr, BpEe, Ps, Pr, ce, senders, receivers, out0, nullptr,
      agg, E_CNT);

  colsum_p1<<<CS_PARTS, 256, 0, stream>>>(agg, partE, N_CNT);  // == colsum(new_edges)
  colsum_p2<<<1, 256, 0, stream>>>(partE, esum);

  // node: relu(agg@Wn_e + nodes@Wn_v + cn)  (K=512, two A segments)
  gemm_core<8, 2><<<(N_CNT + 127) / 128, 512, 0, stream>>>(
      agg, nodes, BpN, nullptr, nullptr, cn, nullptr, nullptr, out1, nullptr,
      nullptr, N_CNT);

  colsum_p1<<<CS_PARTS, 256, 0, stream>>>(out1, partN, N_CNT);
  colsum_p2<<<1, 256, 0, stream>>>(partN, nsum);

  global_mlp<<<1, 512, 0, stream>>>(esum, nsum, gl, Wg, bg, out2);
}

// Round 8
// 449.931 us; speedup vs baseline: 1.4114x; 1.0079x over previous
//
#include <hip/hip_runtime.h>

#define E_CNT 200000
#define N_CNT 50000
#define CS_PARTS 128

typedef __attribute__((ext_vector_type(8))) unsigned short ushort8;
typedef __attribute__((ext_vector_type(4))) unsigned short us4;
typedef __attribute__((ext_vector_type(4))) float f32x4;
typedef __bf16 bf16x8 __attribute__((ext_vector_type(8)));

static __device__ __forceinline__ unsigned short f2bf(float f) {
  unsigned int u = __builtin_bit_cast(unsigned int, f);
  u += 0x7FFFu + ((u >> 16) & 1u);
  return (unsigned short)(u >> 16);
}
static __device__ __forceinline__ float bf2f(unsigned short u) {
  unsigned int x = ((unsigned int)u) << 16;
  return __builtin_bit_cast(float, x);
}
// packed bf16 atomic add (2 elements per 4B op)
static __device__ __forceinline__ void pk_add_bf16(unsigned short* a, unsigned int v) {
  asm volatile("global_atomic_pk_add_bf16 %0, %1, off" ::"v"(a), "v"(v) : "memory");
}

// ---------- fused weight prep ----------
// blocks 0..159: 5 subs x 32 blocks of frag-ready bf16 W conversion
//   sub3 (Wn_e) permutes rows: slot s -> orig (s&~63)|((s&3)<<4)|((s>>2)&15)
// blocks 160/161: ce = be + g@We_g ; cn = bn + g@Wn_g
__global__ void prep_all(const float* __restrict__ We, const float* __restrict__ be,
                         const float* __restrict__ Wn, const float* __restrict__ bn,
                         const float* __restrict__ g, unsigned short* __restrict__ BpEe,
                         unsigned short* __restrict__ BpPs, unsigned short* __restrict__ BpPr,
                         unsigned short* __restrict__ BpN, float* __restrict__ ce,
                         float* __restrict__ cn) {
  int bid = blockIdx.x;
  if (bid >= 160) {
    int j = threadIdx.x;  // 256
    if (bid == 160) {
      float s = be[j];
      for (int k = 0; k < 128; ++k) s += g[k] * We[(size_t)(768 + k) * 256 + j];
      ce[j] = s;
    } else {
      float s = bn[j];
      for (int k = 0; k < 128; ++k) s += g[k] * Wn[(size_t)(512 + k) * 256 + j];
      cn[j] = s;
    }
    return;
  }
  int sub = bid >> 5;
  const float* W;
  unsigned short* Bp;
  bool perm = false;
  if (sub == 0) { W = We;           Bp = BpEe; }
  else if (sub == 1) { W = We + 65536;  Bp = BpPs; }
  else if (sub == 2) { W = We + 131072; Bp = BpPr; }
  else if (sub == 3) { W = Wn;          Bp = BpN; perm = true; }
  else { W = Wn + 65536; Bp = BpN + 65536; }
  int idx = (bid & 31) * 256 + threadIdx.x;  // 0..8191 (KC=8)
  int lane = idx & 63;
  int t = idx >> 6;
  int F = t & 15;
  int kc = t >> 4;
  int col = F * 16 + (lane & 15);
  int kb = kc * 32 + (lane >> 4) * 8;
  ushort8 v;
#pragma unroll
  for (int j = 0; j < 8; ++j) {
    int r = kb + j;
    if (perm) r = (r & ~63) | ((r & 3) << 4) | ((r >> 2) & 15);
    v[j] = f2bf(W[(size_t)r * 256 + col]);
  }
  *reinterpret_cast<ushort8*>(Bp + (size_t)idx * 8) = v;
}

// ---------- unified GEMM core: 128-row x 256-col tile, 8 waves, wave 64x64 ----------
// MODE 0 (PROJ): two halves of grid (nbHalf blocks each) -> Ps / Pr, bf16
//                frag-swizzled slot = wn*64 + lr*4 + fn
// MODE 1 (EDGE): A=edges K=256; v = relu(acc + ce + Ps[snd] + Pr[rcv]);
//                nt-store f32 + pk_add_bf16 into aggB[rcv] (slot layout)
// MODE 2 (NODE): A = [aggB(bf16,slot) | nodes(f32)] K=512; relu(acc+cn); store
template <int NSTEPS, int MODE>
__global__ __launch_bounds__(512, 2) void gemm_core(
    const float* __restrict__ A0, const unsigned short* __restrict__ Ab,
    const float* __restrict__ A1, const unsigned short* __restrict__ Bp,
    const unsigned short* __restrict__ BpAlt, const unsigned short* __restrict__ P1,
    const unsigned short* __restrict__ P2, const float* __restrict__ cvec,
    const int* __restrict__ senders, const int* __restrict__ receivers,
    float* __restrict__ outF, unsigned short* __restrict__ outP,
    unsigned short* __restrict__ outPAlt, unsigned short* __restrict__ aggB,
    int nbHalf, int M) {
  __shared__ unsigned short lds[2][128 * 64];  // bf16 A tiles, XOR-swizzled

  int bid = blockIdx.x;
  const unsigned short* BpL = Bp;
  unsigned short* outPL = outP;
  if (MODE == 0 && bid >= nbHalf) {
    BpL = BpAlt;
    outPL = outPAlt;
    bid -= nbHalf;
  }

  const int tid = threadIdx.x;
  const int lane = tid & 63;
  const int wave = tid >> 6;  // 0..7
  const int wm = wave >> 2;   // 0..1
  const int wn = wave & 3;    // 0..3
  const int q = lane >> 4;    // 0..3
  const int lr = lane & 15;
  const int row0 = bid * 128;

  // staging: thread stages 16 elements of one row per K-step
  const int sr = tid >> 2;  // 0..127
  const int sc = tid & 3;   // 16-elem chunk
  int er = row0 + sr;
  if (er > M - 1) er = M - 1;
  const float* fR = (MODE == 2) ? (A1 + (size_t)er * 256) : (A0 + (size_t)er * 256);
  const unsigned short* bR = (MODE == 2) ? (Ab + (size_t)er * 256) : nullptr;

  const int swz = sr & 7;
  const int wbase = sr * 64;
  const int s0 = ((sc * 2) ^ swz) * 8;
  const int s1 = ((sc * 2 + 1) ^ swz) * 8;

  f32x4 acc[4][4] = {};

  // ---- prologue: stage step 0 ----
  if (MODE == 2) {
    const unsigned short* s = bR + sc * 16;
    *reinterpret_cast<ushort8*>(&lds[0][wbase + s0]) = *reinterpret_cast<const ushort8*>(s);
    *reinterpret_cast<ushort8*>(&lds[0][wbase + s1]) = *reinterpret_cast<const ushort8*>(s + 8);
  } else {
    const float4* p4 = reinterpret_cast<const float4*>(fR + sc * 16);
    float fv[16];
    *reinterpret_cast<float4*>(&fv[0]) = p4[0];
    *reinterpret_cast<float4*>(&fv[4]) = p4[1];
    *reinterpret_cast<float4*>(&fv[8]) = p4[2];
    *reinterpret_cast<float4*>(&fv[12]) = p4[3];
    ushort8 w0, w1;
#pragma unroll
    for (int j = 0; j < 8; ++j) {
      w0[j] = f2bf(fv[j]);
      w1[j] = f2bf(fv[8 + j]);
    }
    *reinterpret_cast<ushort8*>(&lds[0][wbase + s0]) = w0;
    *reinterpret_cast<ushort8*>(&lds[0][wbase + s1]) = w1;
  }
  __syncthreads();

#pragma unroll
  for (int ks = 0; ks < NSTEPS; ++ks) {
    const int cc = ks & 1;

    // B-frags for this step (L2-hot)
    bf16x8 bfr[2][4];
#pragma unroll
    for (int kk = 0; kk < 2; ++kk) {
      const int kc32 = ks * 2 + kk;
#pragma unroll
      for (int fn = 0; fn < 4; ++fn) {
        const int F = wn * 4 + fn;
        bfr[kk][fn] = __builtin_bit_cast(
            bf16x8, *reinterpret_cast<const ushort8*>(
                        BpL + ((size_t)(kc32 * 16 + F) * 64 + lane) * 8));
      }
    }

    // next-step A loads to regs
    float4 nf0, nf1, nf2, nf3;
    ushort8 nb0, nb1;
    const bool nxt_bf = (MODE == 2) && (ks + 1 < 4);
    if (ks + 1 < NSTEPS) {
      if (nxt_bf) {
        const unsigned short* s = bR + (ks + 1) * 64 + sc * 16;
        nb0 = *reinterpret_cast<const ushort8*>(s);
        nb1 = *reinterpret_cast<const ushort8*>(s + 8);
      } else {
        const float* s = fR + ((MODE == 2) ? (ks + 1 - 4) : (ks + 1)) * 64 + sc * 16;
        const float4* p4 = reinterpret_cast<const float4*>(s);
        nf0 = p4[0];
        nf1 = p4[1];
        nf2 = p4[2];
        nf3 = p4[3];
      }
    }

    // MFMA on lds[cc]
#pragma unroll
    for (int kk = 0; kk < 2; ++kk) {
      bf16x8 a[4];
#pragma unroll
      for (int fm = 0; fm < 4; ++fm) {
        int r = wm * 64 + fm * 16 + lr;
        int slot = (kk * 4 + q) ^ (r & 7);
        a[fm] = __builtin_bit_cast(
            bf16x8, *reinterpret_cast<const ushort8*>(&lds[cc][r * 64 + slot * 8]));
      }
#pragma unroll
      for (int fm = 0; fm < 4; ++fm)
#pragma unroll
        for (int fn = 0; fn < 4; ++fn)
          acc[fm][fn] = __builtin_amdgcn_mfma_f32_16x16x32_bf16(
              a[fm], bfr[kk][fn], acc[fm][fn], 0, 0, 0);
    }

    // convert + write next tile
    if (ks + 1 < NSTEPS) {
      ushort8 w0, w1;
      if (nxt_bf) {
        w0 = nb0;
        w1 = nb1;
      } else {
        float fv[16];
        *reinterpret_cast<float4*>(&fv[0]) = nf0;
        *reinterpret_cast<float4*>(&fv[4]) = nf1;
        *reinterpret_cast<float4*>(&fv[8]) = nf2;
        *reinterpret_cast<float4*>(&fv[12]) = nf3;
#pragma unroll
        for (int j = 0; j < 8; ++j) {
          w0[j] = f2bf(fv[j]);
          w1[j] = f2bf(fv[8 + j]);
        }
      }
      *reinterpret_cast<ushort8*>(&lds[cc ^ 1][wbase + s0]) = w0;
      *reinterpret_cast<ushort8*>(&lds[cc ^ 1][wbase + s1]) = w1;
      __syncthreads();
    }
  }

  // ---- epilogue ----
  // D mapping: col = lane&15 (=lr), row = q*4 + i
  float bcol[4];
  if (MODE != 0) {
#pragma unroll
    for (int fn = 0; fn < 4; ++fn) bcol[fn] = cvec[wn * 64 + fn * 16 + lr];
  }
#pragma unroll
  for (int fm = 0; fm < 4; ++fm) {
    int rb = row0 + wm * 64 + fm * 16 + q * 4;
#pragma unroll
    for (int i = 0; i < 4; ++i) {
      int gr = rb + i;
      if (gr < M) {
        if (MODE == 0) {
          us4 pv;
#pragma unroll
          for (int fn = 0; fn < 4; ++fn) pv[fn] = f2bf(acc[fm][fn][i]);
          *reinterpret_cast<us4*>(outPL + (size_t)gr * 256 + wn * 64 + lr * 4) = pv;
        } else if (MODE == 1) {
          int snd = senders[gr], rcv = receivers[gr];
          us4 ps = *reinterpret_cast<const us4*>(P1 + (size_t)snd * 256 + wn * 64 + lr * 4);
          us4 pr = *reinterpret_cast<const us4*>(P2 + (size_t)rcv * 256 + wn * 64 + lr * 4);
          float v[4];
#pragma unroll
          for (int fn = 0; fn < 4; ++fn)
            v[fn] = fmaxf(acc[fm][fn][i] + bcol[fn] + bf2f(ps[fn]) + bf2f(pr[fn]), 0.0f);
#pragma unroll
          for (int fn = 0; fn < 4; ++fn)
            __builtin_nontemporal_store(
                v[fn], &outF[(size_t)gr * 256 + wn * 64 + fn * 16 + lr]);
          unsigned int p01 = (unsigned int)f2bf(v[0]) | ((unsigned int)f2bf(v[1]) << 16);
          unsigned int p23 = (unsigned int)f2bf(v[2]) | ((unsigned int)f2bf(v[3]) << 16);
          unsigned short* ap = aggB + (size_t)rcv * 256 + wn * 64 + lr * 4;
          pk_add_bf16(ap, p01);
          pk_add_bf16(ap + 2, p23);
        } else {
#pragma unroll
          for (int fn = 0; fn < 4; ++fn) {
            int col = wn * 64 + fn * 16 + lr;
            outF[(size_t)gr * 256 + col] = fmaxf(acc[fm][fn][i] + bcol[fn], 0.0f);
          }
        }
      }
    }
  }
}

// ---------- column sums ----------
// f32 input (new_nodes), orig layout -> part (orig order)
__global__ void colsum_p1(const float* __restrict__ in, float* __restrict__ part, int rows) {
  const int c4 = threadIdx.x & 63;
  const int rg = threadIdx.x >> 6;
  f32x4 s = {0.f, 0.f, 0.f, 0.f};
  for (int r = blockIdx.x * 4 + rg; r < rows; r += CS_PARTS * 4)
    s += *reinterpret_cast<const f32x4*>(in + (size_t)r * 256 + c4 * 4);
  __shared__ f32x4 red[256];
  red[threadIdx.x] = s;
  __syncthreads();
  if (rg == 0) {
    f32x4 r = red[c4] + red[64 + c4] + red[128 + c4] + red[192 + c4];
    *reinterpret_cast<f32x4*>(part + (size_t)blockIdx.x * 256 + c4 * 4) = r;
  }
}
__global__ void colsum_p2(const float* __restrict__ part, float* __restrict__ out) {
  const int c = threadIdx.x;  // 256
  float s = 0.f;
  for (int p = 0; p < CS_PARTS; ++p) s += part[(size_t)p * 256 + c];
  out[c] = s;
}
// bf16 slot-layout input (aggB) -> part (slot order)
__global__ void colsum_p1b(const unsigned short* __restrict__ in, float* __restrict__ part,
                           int rows) {
  const int c4 = threadIdx.x & 63;
  const int rg = threadIdx.x >> 6;
  f32x4 s = {0.f, 0.f, 0.f, 0.f};
  for (int r = blockIdx.x * 4 + rg; r < rows; r += CS_PARTS * 4) {
    us4 v = *reinterpret_cast<const us4*>(in + (size_t)r * 256 + c4 * 4);
#pragma unroll
    for (int j = 0; j < 4; ++j) s[j] += bf2f(v[j]);
  }
  __shared__ f32x4 red[256];
  red[threadIdx.x] = s;
  __syncthreads();
  if (rg == 0) {
    f32x4 r = red[c4] + red[64 + c4] + red[128 + c4] + red[192 + c4];
    *reinterpret_cast<f32x4*>(part + (size_t)blockIdx.x * 256 + c4 * 4) = r;
  }
}
// sum parts (slot order) and un-permute: esum[orig(slot)]
__global__ void colsum_p2b(const float* __restrict__ part, float* __restrict__ out) {
  const int s = threadIdx.x;  // 256 (slot)
  float v = 0.f;
  for (int p = 0; p < CS_PARTS; ++p) v += part[(size_t)p * 256 + s];
  int orig = (s & 192) | ((s & 3) << 4) | ((s >> 2) & 15);
  out[orig] = v;
}

// new_globals = relu([esum | nsum | globals] @ Wg + bg), fp32
__global__ void global_mlp(const float* __restrict__ esum, const float* __restrict__ nsum,
                           const float* __restrict__ gl, const float* __restrict__ Wg,
                           const float* __restrict__ bg, float* __restrict__ out2) {
  __shared__ float red[512];
  int g = threadIdx.x & 127;
  int kg = threadIdx.x >> 7;
  float acc = 0.f;
  for (int k = kg; k < 640; k += 4) {
    float x = (k < 256) ? esum[k] : (k < 512 ? nsum[k - 256] : gl[k - 512]);
    acc += x * Wg[(size_t)k * 128 + g];
  }
  red[threadIdx.x] = acc;
  __syncthreads();
  if (kg == 0) {
    float r = red[g] + red[128 + g] + red[256 + g] + red[384 + g] + bg[g];
    out2[g] = fmaxf(r, 0.f);
  }
}

extern "C" void kernel_launch(void* const* d_in, const int* in_sizes, int n_in,
                              void* d_out, int out_size, void* d_ws, size_t ws_size,
                              hipStream_t stream) {
  const float* nodes = (const float*)d_in[0];
  const float* edges = (const float*)d_in[1];
  const float* gl = (const float*)d_in[2];
  const int* senders = (const int*)d_in[3];
  const int* receivers = (const int*)d_in[4];
  const float* We = (const float*)d_in[5];
  const float* be = (const float*)d_in[6];
  const float* Wn = (const float*)d_in[7];
  const float* bn = (const float*)d_in[8];
  const float* Wg = (const float*)d_in[9];
  const float* bg = (const float*)d_in[10];

  float* out0 = (float*)d_out;               // new_edges [200000,256]
  float* out1 = out0 + (size_t)E_CNT * 256;  // new_nodes [50000,256]
  float* out2 = out1 + (size_t)N_CNT * 256;  // new_globals [128]

  char* ws = (char*)d_ws;
  size_t o = 0;
  unsigned short* Ps = (unsigned short*)(ws + o);   o += (size_t)N_CNT * 256 * 2;  // 25.6MB
  unsigned short* Pr = (unsigned short*)(ws + o);   o += (size_t)N_CNT * 256 * 2;  // 25.6MB
  unsigned short* aggB = (unsigned short*)(ws + o); o += (size_t)N_CNT * 256 * 2;  // 25.6MB
  unsigned short* BpEe = (unsigned short*)(ws + o); o += 131072;
  unsigned short* BpPs = (unsigned short*)(ws + o); o += 131072;
  unsigned short* BpPr = (unsigned short*)(ws + o); o += 131072;
  unsigned short* BpN = (unsigned short*)(ws + o);  o += 262144;  // [perm(Wn_e) ; Wn_v]
  float* ce = (float*)(ws + o);                     o += 1024;
  float* cn = (float*)(ws + o);                     o += 1024;
  float* esum = (float*)(ws + o);                   o += 1024;
  float* nsum = (float*)(ws + o);                   o += 1024;
  float* partE = (float*)(ws + o);                  o += CS_PARTS * 256 * 4;
  float* partN = (float*)(ws + o);                  o += CS_PARTS * 256 * 4;

  hipMemsetAsync(aggB, 0, (size_t)N_CNT * 256 * 2, stream);

  prep_all<<<162, 256, 0, stream>>>(We, be, Wn, bn, gl, BpEe, BpPs, BpPr, BpN, ce, cn);

  // both projections in one dispatch: Ps = nodes@We_s, Pr = nodes@We_r
  const int nbN = (N_CNT + 127) / 128;  // 391
  gemm_core<4, 0><<<2 * nbN, 512, 0, stream>>>(
      nodes, nullptr, nullptr, BpPs, BpPr, nullptr, nullptr, nullptr, nullptr,
      nullptr, nullptr, Ps, Pr, nullptr, nbN, N_CNT);

  // edge: relu(edges@We_e + Ps[s] + Pr[r] + ce); pk_add_bf16 segment-sum
  gemm_core<4, 1><<<(E_CNT + 127) / 128, 512, 0, stream>>>(
      edges, nullptr, nullptr, BpEe, nullptr, Ps, Pr, ce, senders, receivers,
      out0, nullptr, nullptr, aggB, 1 << 30, E_CNT);

  colsum_p1b<<<CS_PARTS, 256, 0, stream>>>(aggB, partE, N_CNT);
  colsum_p2b<<<1, 256, 0, stream>>>(partE, esum);  // == colsum(new_edges) mod bf16

  // node: relu(aggB@perm(Wn_e) + nodes@Wn_v + cn)  (K=512)
  gemm_core<8, 2><<<nbN, 512, 0, stream>>>(
      nullptr, aggB, nodes, BpN, nullptr, nullptr, nullptr, cn, nullptr, nullptr,
      out1, nullptr, nullptr, nullptr, 1 << 30, N_CNT);

  colsum_p1<<<CS_PARTS, 256, 0, stream>>>(out1, partN, N_CNT);
  colsum_p2<<<1, 256, 0, stream>>>(partN, nsum);

  global_mlp<<<1, 512, 0, stream>>>(esum, nsum, gl, Wg, bg, out2);
}